// Round 1
// baseline (294.627 us; speedup 1.0000x reference)
//
#include <hip/hip_runtime.h>
#include <math.h>

// Problem constants (reference: B=2, L=19, H=800, W=640, R1=R2=41)
#define NB 2
#define NL 19
#define NH 800
#define NW 640
#define NHW (NH * NW)
#define NMAPS (NB * NL)
#define R1I 41
#define R1SQ 1681.0f
#define INV_R2 (1.0f / 41.0f)
#define WS_STRIDE 8
// ws layout per map m: [m*8+0]=sum_f(logits softplus part), [m*8+1]=sum_x(disk),
//                      [m*8+2]=sum_l1x, [m*8+3]=sum_l1y, [m*8+4]=msum(count)

__device__ __forceinline__ float softplus_part(float x) {
    // max(x,0) + log1p(exp(-|x|)); fast-math variant, rel err ~1e-6 — fine vs 2% thr
    return fmaxf(x, 0.0f) + __logf(1.0f + __expf(-fabsf(x)));
}

// Kernel A: dense reduction over the L logits channels only (77.8 MB).
__global__ __launch_bounds__(256) void bce_dense_kernel(
        const float* __restrict__ fm, float* __restrict__ ws) {
    const int m = blockIdx.y;                 // 0..NMAPS-1
    const int b = m / NL, c = m % NL;
    const float4* __restrict__ base =
        (const float4*)(fm + (size_t)(b * 3 * NL + c) * NHW);
    const int n4 = NHW / 4;                   // 128000
    float s = 0.0f;
    const int stride = gridDim.x * blockDim.x;
    for (int i = blockIdx.x * blockDim.x + threadIdx.x; i < n4; i += stride) {
        float4 v = base[i];
        s += softplus_part(v.x);
        s += softplus_part(v.y);
        s += softplus_part(v.z);
        s += softplus_part(v.w);
    }
    #pragma unroll
    for (int o = 32; o > 0; o >>= 1) s += __shfl_down(s, o, 64);
    __shared__ float sm[4];
    if ((threadIdx.x & 63) == 0) sm[threadIdx.x >> 6] = s;
    __syncthreads();
    if (threadIdx.x == 0)
        atomicAdd(&ws[m * WS_STRIDE + 0], sm[0] + sm[1] + sm[2] + sm[3]);
}

// Kernel B: per-map disk sums over the <=83x83 bounding box. 16 blocks/map.
#define BPM 16
__global__ __launch_bounds__(256) void disk_kernel(
        const float* __restrict__ fm, const float* __restrict__ lm,
        float* __restrict__ ws) {
    const int m   = blockIdx.x / BPM;
    const int sub = blockIdx.x % BPM;
    const int b = m / NL, c = m % NL;
    const float X = rintf(lm[(b * NL + c) * 2 + 0] * (float)(NH - 1));
    const float Y = rintf(lm[(b * NL + c) * 2 + 1] * (float)(NW - 1));
    const int Xi = (int)X, Yi = (int)Y;
    const int i0 = max(0, Xi - R1I), i1 = min(NH - 1, Xi + R1I);
    const int j0 = max(0, Yi - R1I), j1 = min(NW - 1, Yi + R1I);
    const int ni = i1 - i0 + 1, nj = j1 - j0 + 1;
    const int tot = ni * nj;

    const float* __restrict__ logit = fm + (size_t)(b * 3 * NL + c) * NHW;
    const float* __restrict__ px = logit + (size_t)NL * NHW;
    const float* __restrict__ py = px + (size_t)NL * NHW;

    float sx = 0.f, slx = 0.f, sly = 0.f, cnt = 0.f;
    for (int idx = sub * blockDim.x + threadIdx.x; idx < tot;
         idx += BPM * blockDim.x) {
        const int i = i0 + idx / nj;
        const int j = j0 + idx % nj;
        const float dx = X - (float)i;
        const float dy = Y - (float)j;
        if (dx * dx + dy * dy <= R1SQ) {
            const size_t o = (size_t)i * NW + j;
            sx  += logit[o];
            slx += fabsf(px[o] - dx * INV_R2);
            sly += fabsf(py[o] - dy * INV_R2);
            cnt += 1.0f;
        }
    }
    // wave-level reduce, lane0 of each wave does the atomic (38*4 addresses)
    #pragma unroll
    for (int o = 32; o > 0; o >>= 1) {
        sx  += __shfl_down(sx, o, 64);
        slx += __shfl_down(slx, o, 64);
        sly += __shfl_down(sly, o, 64);
        cnt += __shfl_down(cnt, o, 64);
    }
    if ((threadIdx.x & 63) == 0) {
        float* p = ws + m * WS_STRIDE;
        atomicAdd(p + 1, sx);
        atomicAdd(p + 2, slx);
        atomicAdd(p + 3, sly);
        atomicAdd(p + 4, cnt);
    }
}

// Kernel C: combine 38 maps -> scalar loss.
__global__ __launch_bounds__(64) void final_kernel(
        const float* __restrict__ ws, float* __restrict__ out) {
    const int t = threadIdx.x;
    float v = 0.0f;
    if (t < NMAPS) {
        const float* p = ws + t * WS_STRIDE;
        const float sf = p[0], sx = p[1], slx = p[2], sly = p[3], cnt = p[4];
        // bce = 2*(sum_f - sum_x_disk)/HW ; l1 = (slx+sly)/msum
        v = 2.0f * (sf - sx) / (float)NHW + (slx + sly) / cnt;
    }
    #pragma unroll
    for (int o = 32; o > 0; o >>= 1) v += __shfl_down(v, o, 64);
    if (t == 0) out[0] = v / (float)NMAPS;
}

extern "C" void kernel_launch(void* const* d_in, const int* in_sizes, int n_in,
                              void* d_out, int out_size, void* d_ws, size_t ws_size,
                              hipStream_t stream) {
    const float* fm = (const float*)d_in[0];   // (2, 57, 800, 640) fp32
    const float* lm = (const float*)d_in[1];   // (2, 19, 2) fp32
    float* out = (float*)d_out;                // scalar fp32
    float* ws  = (float*)d_ws;

    hipMemsetAsync(d_ws, 0, NMAPS * WS_STRIDE * sizeof(float), stream);

    dim3 gA(64, NMAPS);                        // 2432 blocks x 256 thr
    bce_dense_kernel<<<gA, 256, 0, stream>>>(fm, ws);
    disk_kernel<<<NMAPS * BPM, 256, 0, stream>>>(fm, lm, ws);
    final_kernel<<<1, 64, 0, stream>>>(ws, out);
}

// Round 2
// 279.990 us; speedup vs baseline: 1.0523x; 1.0523x over previous
//
#include <hip/hip_runtime.h>
#include <math.h>

// Problem constants (reference: B=2, L=19, H=800, W=640, R1=R2=41)
#define NB 2
#define NL 19
#define NH 800
#define NW 640
#define NHW (NH * NW)
#define NMAPS (NB * NL)          // 38
#define R1I 41
#define R1SQ 1681.0f
#define INV_R2 (1.0f / 41.0f)

// Grid layout for the fused kernel:
//   blocks [0, DENSE_BLOCKS)              : dense softplus sum, 64 blocks/map
//   blocks [DENSE_BLOCKS, DENSE+DISK)     : disk sums, 16 blocks/map
#define SUB_DENSE 64
#define SUB_DISK  16
#define DENSE_BLOCKS (NMAPS * SUB_DENSE)   // 2432
#define DISK_BLOCKS  (NMAPS * SUB_DISK)    // 608
#define TOTAL_BLOCKS (DENSE_BLOCKS + DISK_BLOCKS)

// ws layout (floats), ALL slots written unconditionally -> no zero-init needed:
//   [m*64 + sub]                               dense partial (2432 floats)
//   [2432 + (m*16 + sub)*4 + {0,1,2,3}]        disk partials sx,slx,sly,cnt (2432 floats)
#define WS_DISK_BASE DENSE_BLOCKS

__device__ __forceinline__ float softplus_part(float x) {
    // max(x,0) + log1p(exp(-|x|)); fast-math variant, rel err ~1e-6
    return fmaxf(x, 0.0f) + __logf(1.0f + __expf(-fabsf(x)));
}

__global__ __launch_bounds__(256) void fused_main_kernel(
        const float* __restrict__ fm, const float* __restrict__ lm,
        float* __restrict__ ws) {
    const int blk = blockIdx.x;
    __shared__ float sm[4 * 4];

    if (blk < DENSE_BLOCKS) {
        // ---- dense softplus over logits channel of map m ----
        const int m = blk / SUB_DENSE, sub = blk % SUB_DENSE;
        const int b = m / NL, c = m % NL;
        const float4* __restrict__ base =
            (const float4*)(fm + (size_t)(b * 3 * NL + c) * NHW);
        const int n4 = NHW / 4;                       // 128000
        float s = 0.0f;
        const int stride = SUB_DENSE * blockDim.x;    // 16384
        for (int i = sub * blockDim.x + threadIdx.x; i < n4; i += stride) {
            float4 v = base[i];
            s += softplus_part(v.x);
            s += softplus_part(v.y);
            s += softplus_part(v.z);
            s += softplus_part(v.w);
        }
        #pragma unroll
        for (int o = 32; o > 0; o >>= 1) s += __shfl_down(s, o, 64);
        if ((threadIdx.x & 63) == 0) sm[threadIdx.x >> 6] = s;
        __syncthreads();
        if (threadIdx.x == 0)
            ws[m * SUB_DENSE + sub] = sm[0] + sm[1] + sm[2] + sm[3];
    } else {
        // ---- disk sums over the <=83x83 bounding box of map m ----
        const int d = blk - DENSE_BLOCKS;
        const int m = d / SUB_DISK, sub = d % SUB_DISK;
        const int b = m / NL, c = m % NL;
        const float X = rintf(lm[(b * NL + c) * 2 + 0] * (float)(NH - 1));
        const float Y = rintf(lm[(b * NL + c) * 2 + 1] * (float)(NW - 1));
        const int Xi = (int)X, Yi = (int)Y;
        const int i0 = max(0, Xi - R1I), i1 = min(NH - 1, Xi + R1I);
        const int j0 = max(0, Yi - R1I), j1 = min(NW - 1, Yi + R1I);
        const int ni = i1 - i0 + 1, nj = j1 - j0 + 1;
        const int tot = ni * nj;

        const float* __restrict__ logit = fm + (size_t)(b * 3 * NL + c) * NHW;
        const float* __restrict__ px = logit + (size_t)NL * NHW;
        const float* __restrict__ py = px + (size_t)NL * NHW;

        float sx = 0.f, slx = 0.f, sly = 0.f, cnt = 0.f;
        for (int idx = sub * blockDim.x + threadIdx.x; idx < tot;
             idx += SUB_DISK * blockDim.x) {
            const int i = i0 + idx / nj;
            const int j = j0 + idx % nj;
            const float dx = X - (float)i;
            const float dy = Y - (float)j;
            if (dx * dx + dy * dy <= R1SQ) {
                const size_t o = (size_t)i * NW + j;
                sx  += logit[o];
                slx += fabsf(px[o] - dx * INV_R2);
                sly += fabsf(py[o] - dy * INV_R2);
                cnt += 1.0f;
            }
        }
        #pragma unroll
        for (int o = 32; o > 0; o >>= 1) {
            sx  += __shfl_down(sx, o, 64);
            slx += __shfl_down(slx, o, 64);
            sly += __shfl_down(sly, o, 64);
            cnt += __shfl_down(cnt, o, 64);
        }
        const int w = threadIdx.x >> 6;
        if ((threadIdx.x & 63) == 0) {
            sm[w * 4 + 0] = sx; sm[w * 4 + 1] = slx;
            sm[w * 4 + 2] = sly; sm[w * 4 + 3] = cnt;
        }
        __syncthreads();
        if (threadIdx.x == 0) {
            float4 r;
            r.x = sm[0] + sm[4] + sm[8]  + sm[12];
            r.y = sm[1] + sm[5] + sm[9]  + sm[13];
            r.z = sm[2] + sm[6] + sm[10] + sm[14];
            r.w = sm[3] + sm[7] + sm[11] + sm[15];
            ((float4*)(ws + WS_DISK_BASE))[m * SUB_DISK + sub] = r;
        }
    }
}

// Final: combine all partials -> scalar loss. One block, 256 threads.
__global__ __launch_bounds__(256) void final_kernel(
        const float* __restrict__ ws, float* __restrict__ out) {
    __shared__ float cat[5][NMAPS];
    __shared__ float vm[NMAPS];
    const int t = threadIdx.x;
    if (t < 5 * NMAPS) {
        const int ci = t / NMAPS, m = t % NMAPS;
        float s = 0.0f;
        if (ci == 0) {
            #pragma unroll 8
            for (int i = 0; i < SUB_DENSE; ++i) s += ws[m * SUB_DENSE + i];
        } else {
            const int k = ci - 1;
            #pragma unroll 8
            for (int i = 0; i < SUB_DISK; ++i)
                s += ws[WS_DISK_BASE + (m * SUB_DISK + i) * 4 + k];
        }
        cat[ci][m] = s;
    }
    __syncthreads();
    if (t < NMAPS) {
        vm[t] = 2.0f * (cat[0][t] - cat[1][t]) / (float)NHW
              + (cat[2][t] + cat[3][t]) / cat[4][t];
    }
    __syncthreads();
    if (t == 0) {
        float v = 0.0f;
        #pragma unroll
        for (int m = 0; m < NMAPS; ++m) v += vm[m];
        out[0] = v / (float)NMAPS;
    }
}

extern "C" void kernel_launch(void* const* d_in, const int* in_sizes, int n_in,
                              void* d_out, int out_size, void* d_ws, size_t ws_size,
                              hipStream_t stream) {
    const float* fm = (const float*)d_in[0];   // (2, 57, 800, 640) fp32
    const float* lm = (const float*)d_in[1];   // (2, 19, 2) fp32
    float* out = (float*)d_out;                // scalar fp32
    float* ws  = (float*)d_ws;

    fused_main_kernel<<<TOTAL_BLOCKS, 256, 0, stream>>>(fm, lm, ws);
    final_kernel<<<1, 256, 0, stream>>>(ws, out);
}